// Round 10
// baseline (119.030 us; speedup 1.0000x reference)
//
#include <hip/hip_runtime.h>

#define T_SEQ 4096
#define BATCH 4
#define DD 128
#define BT (BATCH * T_SEQ)
#define MAXPARTS 16       // parts per group = ceil((sg+1)/2) <= 16

typedef __bf16 bf16x8 __attribute__((ext_vector_type(8)));
typedef float f32x4 __attribute__((ext_vector_type(4)));

__device__ inline bf16x8 ld8(const unsigned short* p) {
  return *reinterpret_cast<const bf16x8*>(p);
}
__device__ inline unsigned short bfc(float f) {
  __bf16 v = (__bf16)f;
  return __builtin_bit_cast(unsigned short, v);
}
__device__ inline float fexp2(float x) {
  float r;
  asm("v_exp_f32 %0, %1" : "=v"(r) : "v"(x));
  return r;
}
// V-buffer swizzle: XOR the 16B slot with (row>>1)&3 (bits 3-4 of the short
// index from bits 6-7). 16B-granule-preserving, involution.
__device__ inline int vsw(int sIdx) {
  return sIdx ^ ((((sIdx >> 6) & 3) << 3));
}
// async global->LDS, 16B per lane (m97-proven pattern). LDS dest must be
// lane-linear (base + lane*16); swizzles go on the GLOBAL source (rule #21).
__device__ inline void glds16(const unsigned short* g, unsigned short* l) {
  __builtin_amdgcn_global_load_lds(
      (const __attribute__((address_space(1))) unsigned int*)(g),
      (__attribute__((address_space(3))) unsigned int*)(l), 16, 0, 0);
}

#define MFMA(a, b, c) __builtin_amdgcn_mfma_f32_16x16x32_bf16((a), (b), (c), 0, 0, 0)

// ---- W (128x128 f32, [d][u]) -> frag-major bf16:
// F[((n0*4+c)*64 + lane)*8 + j] = W[(c*32+g*8+j)*128 + n0*16+t], lane=(g<<4)|t.
__global__ void wt_kernel(const float* __restrict__ Wq, const float* __restrict__ Wk,
                          const float* __restrict__ Wv,
                          unsigned short* __restrict__ fq, unsigned short* __restrict__ fk,
                          unsigned short* __restrict__ fv) {
  const float* W = (blockIdx.y == 0) ? Wq : (blockIdx.y == 1) ? Wk : Wv;
  unsigned short* F = (blockIdx.y == 0) ? fq : (blockIdx.y == 1) ? fk : fv;
  int e = blockIdx.x * 256 + threadIdx.x;          // 0..16383
  int j = e & 7, lane = (e >> 3) & 63, nc = e >> 9;
  int c = nc & 3, n0 = nc >> 2;
  int t = lane & 15, g = lane >> 4;
  F[e] = bfc(W[(c * 32 + g * 8 + j) * 128 + n0 * 16 + t]);
}

// ---- projections, W-STATIONARY (unchanged, proven). qf folds (1/64)*log2(e).
__global__ __launch_bounds__(256) void proj_kernel(
    const float* __restrict__ X,
    const unsigned short* __restrict__ fq,
    const unsigned short* __restrict__ fk,
    const unsigned short* __restrict__ fv,
    unsigned short* __restrict__ qf,
    unsigned short* __restrict__ kf,
    unsigned short* __restrict__ vt) {
  const int tid = threadIdx.x;
  const int w = tid >> 6, lane = tid & 63;
  const int t = lane & 15, g = lane >> 4;
  const int r0 = blockIdx.x * 32;   // 512 blocks x 32 rows

  __shared__ unsigned short xs[2][16 * 136];

  bf16x8 wq[2][4], wk[2][4], wv[2][4];
#pragma unroll
  for (int s = 0; s < 2; ++s)
#pragma unroll
    for (int c = 0; c < 4; ++c) {
      int fo = (((w + s * 4) * 4 + c) * 64 + lane) * 8;
      wq[s][c] = ld8(fq + fo);
      wk[s][c] = ld8(fk + fo);
      wv[s][c] = ld8(fv + fo);
    }

#pragma unroll
  for (int sub = 0; sub < 2; ++sub) {
    int r = tid >> 4, cb = tid & 15;
    const float* xp = X + (size_t)(r0 + sub * 16 + r) * DD + cb * 8;
    float4 lo = *reinterpret_cast<const float4*>(xp);
    float4 hi = *reinterpret_cast<const float4*>(xp + 4);
    bf16x8 tmp;
    tmp[0] = (__bf16)lo.x; tmp[1] = (__bf16)lo.y; tmp[2] = (__bf16)lo.z; tmp[3] = (__bf16)lo.w;
    tmp[4] = (__bf16)hi.x; tmp[5] = (__bf16)hi.y; tmp[6] = (__bf16)hi.z; tmp[7] = (__bf16)hi.w;
    *reinterpret_cast<bf16x8*>(&xs[sub][r * 136 + cb * 8]) = tmp;
  }
  __syncthreads();

#pragma unroll
  for (int sub = 0; sub < 2; ++sub) {
    const int r0s = r0 + sub * 16;
    bf16x8 x[4];
#pragma unroll
    for (int c = 0; c < 4; ++c)
      x[c] = ld8(&xs[sub][t * 136 + c * 32 + g * 8]);

#pragma unroll
    for (int s = 0; s < 2; ++s) {
      const int n0 = w + s * 4;
      f32x4 aq = {0.f, 0.f, 0.f, 0.f}, ak = {0.f, 0.f, 0.f, 0.f};
#pragma unroll
      for (int c = 0; c < 4; ++c) {
        aq = MFMA(x[c], wq[s][c], aq);
        ak = MFMA(x[c], wk[s][c], ak);
      }
      const int cP = n0 >> 1;
      const int Gp = ((n0 & 1) << 1) | (t >> 3);
      const int ep = t & 7;
#pragma unroll
      for (int r = 0; r < 4; ++r) {
        int row = r0s + g * 4 + r;
        size_t qoff = ((size_t)((row >> 4) * 4 + cP) * 64 + ((Gp << 4) | (row & 15))) * 8 + ep;
        qf[qoff] = bfc(aq[r] * 0.0225421101f);   // (1/64) * log2(e)
        int tp = (row & 3) | (((row >> 3) & 3) << 2);
        size_t koff =
            ((size_t)(((row >> 5) * 2 + ((row >> 2) & 1)) * 4 + cP) * 64 + ((Gp << 4) | tp)) * 8 +
            ep;
        kf[koff] = bfc(ak[r]);
      }
    }

    const int key = r0s + t;
    const size_t vbase = (size_t)(key >> 5) * 4096 + (key & 31);
#pragma unroll
    for (int s = 0; s < 2; ++s) {
      const int u0 = w + s * 4;
      f32x4 av = {0.f, 0.f, 0.f, 0.f};
#pragma unroll
      for (int c = 0; c < 4; ++c)
        av = MFMA(wv[s][c], x[c], av);
#pragma unroll
      for (int r = 0; r < 4; ++r)
        vt[vbase + (size_t)(u0 * 16 + g * 4 + r) * 32] = bfc(av[r]);
    }
  }
}

// ---- flash attention, occupancy round: LDS-shared K/V (4 waves, one 128-row
// q-group, wave w owns tile 4*sg+w), KVBLK=32, staging via async
// global_load_lds (no staging VGPRs -> no r3/r4 spill trigger; V swizzle
// moved to the global SOURCE address, LDS dest linear, reads vsw'd).
// Parts <= 8 chunks: per batch sum ceil((sg+1)/2) = 272 blocks -> grid 1088,
// ~4 blocks/CU supply; launch_bounds(256,3) -> 3 blocks/CU co-resident =
// 12 waves/CU (r9 averaged ~5): independent barrier streams finally overlap
// the per-iteration stage-wait/barrier-drain serial chain. Work-descending
// dispatch (a = 271-k) puts 8-chunk parts first, 1-4 chunk parts last.
__global__ __launch_bounds__(256, 3) void attn_kernel(
    const unsigned short* __restrict__ qf,
    const unsigned short* __restrict__ kf,
    const unsigned short* __restrict__ vt,
    float* __restrict__ pO,
    float* __restrict__ pL,
    float* __restrict__ out) {
  const int tid = threadIdx.x;
  const int w = tid >> 6, lane = tid & 63;
  const int t = lane & 15, G = lane >> 4;
  const int bi = blockIdx.x;
  const int xcd = bi & 7;                      // assumed round-robin XCD mapping
  const int b = xcd >> 1;                      // batch pinned to an XCD pair (L2)
  const int k = ((bi >> 3) << 1) | (xcd & 1);  // 0..271 batch-local block index

  // decode: a = 271-k ascending enum -> (group sg, part p); parts/group =
  // ceil((sg+1)/2), cumulative found incrementally (<=32 scalar iterations).
  const int a = 271 - k;
  int sg = 0, cacc = 0;
  for (;;) {
    const int pg = (sg + 2) >> 1;
    if (cacc + pg <= a) { cacc += pg; ++sg; } else break;
  }
  const int p = a - cacc;
  const int P = (sg + 2) >> 1;
  const int N = 4 * sg + 4;                    // 32-key chunks in this group
  const int qn = N / P, rem = N % P;           // balanced split, parts <= 8
  const int jlo = p * qn + min(p, rem);
  const int jhi = jlo + qn + (p < rem ? 1 : 0);

  const int sig32 = 4 * sg + w;                // this wave's 32-row tile
  const int q0 = sig32 * 32;

  const unsigned short* kfb = kf + (size_t)b * (T_SEQ * DD);
  const unsigned short* vtb = vt + (size_t)b * (T_SEQ * DD);

  __shared__ unsigned short bufK[2][4096], bufV[2][4096];

  // Q fragments for tiles 2*sig32, 2*sig32+1
  bf16x8 qa[2][4];
#pragma unroll
  for (int pp = 0; pp < 2; ++pp)
#pragma unroll
    for (int c = 0; c < 4; ++c)
      qa[pp][c] = ld8(qf + ((size_t)((b * 256 + 2 * sig32 + pp) * 4 + c) * 64 + lane) * 8);

  f32x4 O[2][8];
#pragma unroll
  for (int pp = 0; pp < 2; ++pp)
#pragma unroll
    for (int u0 = 0; u0 < 8; ++u0) O[pp][u0] = (f32x4){0.f, 0.f, 0.f, 0.f};
  float ls0 = 0.f, ls1 = 0.f;

  // async stage of chunk jj into buffer sel (16 KB: 4 x 16B DMA per thread)
  auto stage = [&](int sel, int jj) {
    const unsigned short* kch = kfb + (size_t)jj * 4096;
    const unsigned short* vch = vtb + (size_t)jj * 4096;
    glds16(kch + tid * 8,             &bufK[sel][tid * 8]);
    glds16(kch + 2048 + tid * 8,      &bufK[sel][2048 + tid * 8]);
    glds16(vch + vsw(tid * 8),        &bufV[sel][tid * 8]);
    glds16(vch + 2048 + vsw(tid * 8), &bufV[sel][2048 + tid * 8]);
  };

  stage(0, jlo);
  __syncthreads();   // drains vmcnt(0): buf0 staged

  int cur = 0;
  for (int j = jlo; j < jhi; ++j) {
    // issue next chunk's DMA into the other buffer; latency hides under
    // this iteration's compute, drained by the end-of-iteration barrier
    if (j + 1 < jhi) stage(cur ^ 1, j + 1);

    if (j <= sig32) {                          // wave-uniform causal skip
      f32x4 s00 = {0.f, 0.f, 0.f, 0.f}, s01 = {0.f, 0.f, 0.f, 0.f};
      f32x4 s10 = {0.f, 0.f, 0.f, 0.f}, s11 = {0.f, 0.f, 0.f, 0.f};
      {
        bf16x8 kc[4];
#pragma unroll
        for (int c = 0; c < 4; ++c) kc[c] = ld8(&bufK[cur][c * 512 + lane * 8]);
        __builtin_amdgcn_s_setprio(1);
#pragma unroll
        for (int c = 0; c < 4; ++c) {
          s00 = MFMA(kc[c], qa[0][c], s00);
          s10 = MFMA(kc[c], qa[1][c], s10);
        }
        __builtin_amdgcn_s_setprio(0);
#pragma unroll
        for (int c = 0; c < 4; ++c) kc[c] = ld8(&bufK[cur][(4 + c) * 512 + lane * 8]);
        __builtin_amdgcn_s_setprio(1);
#pragma unroll
        for (int c = 0; c < 4; ++c) {
          s01 = MFMA(kc[c], qa[0][c], s01);
          s11 = MFMA(kc[c], qa[1][c], s11);
        }
        __builtin_amdgcn_s_setprio(0);
      }

      bf16x8 pb0, pb1;
      if (j < sig32) {
        // fully-unmasked chunk: no causal compares
#pragma unroll
        for (int r = 0; r < 4; ++r) {
          float e00 = fexp2(s00[r]), e01 = fexp2(s01[r]);
          float e10 = fexp2(s10[r]), e11 = fexp2(s11[r]);
          ls0 += e00 + e01;
          ls1 += e10 + e11;
          pb0[r] = (__bf16)e00; pb0[r + 4] = (__bf16)e01;
          pb1[r] = (__bf16)e10; pb1[r + 4] = (__bf16)e11;
        }
      } else {
        // diagonal chunk (j == sig32)
#pragma unroll
        for (int r = 0; r < 4; ++r) {
          int k0 = j * 32 + G * 8 + r;
          float e00 = (k0 <= q0 + t) ? fexp2(s00[r]) : 0.f;
          float e01 = (k0 + 4 <= q0 + t) ? fexp2(s01[r]) : 0.f;
          float e10 = (k0 <= q0 + 16 + t) ? fexp2(s10[r]) : 0.f;
          float e11 = (k0 + 4 <= q0 + 16 + t) ? fexp2(s11[r]) : 0.f;
          ls0 += e00 + e01;
          ls1 += e10 + e11;
          pb0[r] = (__bf16)e00; pb0[r + 4] = (__bf16)e01;
          pb1[r] = (__bf16)e10; pb1[r + 4] = (__bf16)e11;
        }
      }

      __builtin_amdgcn_s_setprio(1);
#pragma unroll
      for (int u0 = 0; u0 < 8; ++u0) {
        bf16x8 vcu = ld8(&bufV[cur][vsw((u0 * 16 + t) * 32 + G * 8)]);
        O[0][u0] = MFMA(pb0, vcu, O[0][u0]);
        O[1][u0] = MFMA(pb1, vcu, O[1][u0]);
      }
      __builtin_amdgcn_s_setprio(0);
    }

    __syncthreads();   // drains the async stage; protects buffer swap
    cur ^= 1;
  }

  // ---- epilogue: one flush per block
  float r0s = ls0; r0s += __shfl_xor(r0s, 16); r0s += __shfl_xor(r0s, 32);
  float r1s = ls1; r1s += __shfl_xor(r1s, 16); r1s += __shfl_xor(r1s, 32);
  if (P == 1) {
    // whole group in this block: each wave normalizes + stores its tile
    float linv0[4], linv1[4];
#pragma unroll
    for (int r = 0; r < 4; ++r) {
      linv0[r] = 1.0f / __shfl(r0s, G * 4 + r);
      linv1[r] = 1.0f / __shfl(r1s, G * 4 + r);
    }
    float* op0 = out + ((size_t)(b * T_SEQ + q0 + G * 4)) * DD + t;
    float* op1 = op0 + (size_t)16 * DD;
#pragma unroll
    for (int u0 = 0; u0 < 8; ++u0) {
#pragma unroll
      for (int r = 0; r < 4; ++r) {
        op0[(size_t)r * DD + u0 * 16] = O[0][u0][r] * linv0[r];
        op1[(size_t)r * DD + u0 * 16] = O[1][u0][r] * linv1[r];
      }
    }
  } else {
    // split group: raw per-wave partial to workspace slot (b, sig32, p)
    const int slot = (b * 128 + sig32) * MAXPARTS + p;
    if (lane < 16) {
      pL[slot * 32 + lane] = r0s;
      pL[slot * 32 + 16 + lane] = r1s;
    }
    float* pb = pO + (size_t)slot * 4096 + (size_t)(G * 4) * DD + t;
#pragma unroll
    for (int u0 = 0; u0 < 8; ++u0) {
#pragma unroll
      for (int r = 0; r < 4; ++r) {
        pb[(size_t)r * DD + u0 * 16] = O[0][u0][r];
        pb[(size_t)(16 + r) * DD + u0 * 16] = O[1][u0][r];
      }
    }
  }
}

// ---- combine split groups: sum <=16 per-part partials, normalize, store.
__global__ __launch_bounds__(256) void comb_kernel(const float* __restrict__ pO,
                                                   const float* __restrict__ pL,
                                                   float* __restrict__ out) {
  const int bi = blockIdx.x;          // 512: b = bi>>7, sig32 = bi&127
  const int b = bi >> 7, sig32 = bi & 127;
  const int sg = sig32 >> 2;
  const int parts = (sg + 2) >> 1;
  if (parts == 1) return;             // handled directly by attn_kernel
  const int tid = threadIdx.x;
  const int q = tid >> 3, uc = (tid & 7) * 16;
  const int slot0 = (b * 128 + sig32) * MAXPARTS;

  float ls = 0.f;
  for (int p = 0; p < parts; ++p) ls += pL[(slot0 + p) * 32 + q];
  const float linv = 1.0f / ls;

  float4 acc[4] = {{0,0,0,0},{0,0,0,0},{0,0,0,0},{0,0,0,0}};
  for (int p = 0; p < parts; ++p) {
    const float* src = pO + (size_t)(slot0 + p) * 4096 + (size_t)q * DD + uc;
#pragma unroll
    for (int e = 0; e < 4; ++e) {
      float4 v = *reinterpret_cast<const float4*>(src + e * 4);
      acc[e].x += v.x; acc[e].y += v.y; acc[e].z += v.z; acc[e].w += v.w;
    }
  }
  float* dst = out + ((size_t)(b * T_SEQ + sig32 * 32 + q)) * DD + uc;
#pragma unroll
  for (int e = 0; e < 4; ++e) {
    acc[e].x *= linv; acc[e].y *= linv; acc[e].z *= linv; acc[e].w *= linv;
    *reinterpret_cast<float4*>(dst + e * 4) = acc[e];
  }
}

extern "C" void kernel_launch(void* const* d_in, const int* in_sizes, int n_in,
                              void* d_out, int out_size, void* d_ws, size_t ws_size,
                              hipStream_t stream) {
  const float* X  = (const float*)d_in[0];
  const float* Wq = (const float*)d_in[1];
  const float* Wk = (const float*)d_in[2];
  const float* Wv = (const float*)d_in[3];
  float* out = (float*)d_out;

  unsigned short* qf = (unsigned short*)d_ws;          // frag-major Q [BT/16][4][64][8]
  unsigned short* kf = qf + (size_t)BT * DD;            // frag-major K [BT/32][2][4][64][8]
  unsigned short* vt = kf + (size_t)BT * DD;            // k-blocked V^T [BT/32][128][32]
  unsigned short* fq = vt + (size_t)BT * DD;            // frag-major W (16384 each)
  unsigned short* fk = fq + DD * DD;
  unsigned short* fv = fk + DD * DD;
  float* pO = (float*)(fv + DD * DD);                   // partials [4*128*16][32][128]
  float* pL = pO + (size_t)BATCH * 128 * MAXPARTS * 32 * 128;  // rowsums [...][32]

  dim3 wt_grid(64, 3);
  wt_kernel<<<wt_grid, 256, 0, stream>>>(Wq, Wk, Wv, fq, fk, fv);
  proj_kernel<<<BT / 32, 256, 0, stream>>>(X, fq, fk, fv, qf, kf, vt);
  attn_kernel<<<1088, 256, 0, stream>>>(qf, kf, vt, pO, pL, out);
  comb_kernel<<<512, 256, 0, stream>>>(pO, pL, out);
}